// Round 1
// baseline (240.646 us; speedup 1.0000x reference)
//
#include <hip/hip_runtime.h>
#include <string.h>

// Problem constants
constexpr int cB = 64, cS = 512, cN = 512, cM = 128, cUNF = 6;
constexpr float cDELTA = 0.016666666666666666f;  // DT/UNFOLDS = 0.1/6

// Fused MFMA design (r16):
//   In the measured config sigma==mu==0.5 (recurrent AND sensory), so the
//   gate is clamp01(v[b,i]) -- independent of j. Each unfold is then two
//   [64x512]x[512x512] matmuls (vs erev*mask and w*mask): 67 MFLOP/unfold,
//   i.e. latency-bound, not throughput-bound.
//   - 32 blocks x 256 thr; block owns j-slice of 16 columns.
//   - Weights held as f16 MFMA B-fragments in REGISTERS for the entire
//     kernel (gathered once): no EW pack kernel, no per-unfold weight reads.
//   - Sensory reduction via the same MFMA path (fragment regs reused).
//   - v exchanged through ping-pong f32 agent buffers + the proven
//     generation-slot barrier (harness poison is negative as int; gens 1..6).
//   - Per-lane-owned (b,j) cells: v, s_rev+bias, s_w, tau all in registers.
//   - General (non-uniform sigma/mu) fallback: slow VALU loops per block,
//     reading the f32 v buffer. Correct, unexercised by the bench.
constexpr int JT   = 16;            // j-columns per block
constexpr int NBLK = cN / JT;       // 32 blocks
constexpr int NT   = 256;           // 4 waves; wave = M-tile (16 batches)
constexpr int SLOT_STRIDE = 16;     // ints; 64 B slot spacing

// ws layout (float offsets)
constexpr size_t OFF_V0   = 0;                         // [B][N] f32 ping
constexpr size_t OFF_V1   = (size_t)cB * cN;           // [B][N] f32 pong
constexpr size_t OFF_SLOT = OFF_V1 + (size_t)cB * cN;  // 32 slots x 16 ints

typedef _Float16 half8 __attribute__((ext_vector_type(8)));
typedef float    floatx4 __attribute__((ext_vector_type(4)));

__device__ __forceinline__ float clamp01(float x) {
    return __builtin_amdgcn_fmed3f(x, 0.0f, 1.0f);
}

__global__ __launch_bounds__(NT, 1)
void k_fused(const float* __restrict__ inputs, const float* __restrict__ states,
             const float* __restrict__ tau,    const float* __restrict__ bias,
             const float* __restrict__ erev,   const float* __restrict__ wgt,
             const float* __restrict__ sigma,  const float* __restrict__ mu,
             const float* __restrict__ serev,  const float* __restrict__ swgt,
             const float* __restrict__ ssigma, const float* __restrict__ smu,
             const float* __restrict__ mask,   const float* __restrict__ smask,
             const float* __restrict__ inw,    const float* __restrict__ inb,
             const float* __restrict__ outw,   const float* __restrict__ outb,
             float* __restrict__ out, float* __restrict__ ws)
{
    float* v0 = ws + OFF_V0;
    float* v1 = ws + OFF_V1;
    int* slots = (int*)(ws + OFF_SLOT);

    const int tid  = threadIdx.x;
    const int blk  = blockIdx.x;
    const int j0   = blk * JT;
    const int lane = tid & 63;
    const int mt   = tid >> 6;          // wave id == M-tile (batch group of 16)
    const int lr   = lane & 15;         // row/col index within 16x16 tile
    const int lg   = lane >> 4;         // k-group (A/B), row-group (C/D)
    const int bj   = j0 + lr;           // this lane's output column j (B/C)
    const int arow = mt * 16 + lr;      // this lane's A-fragment row (batch)
    const int kbase = lg * 8;           // k offset inside a K=32 step
    const int cb0  = mt * 16 + lg * 4;  // first owned batch row (C mapping)

    int* mySlot = slots + blk * SLOT_STRIDE;
    __shared__ int flagR, flagS;

    // ---- per-lane owned cells: (b = cb0+r, j = bj), r = 0..3 ----
    float vold[4];
    const float tau_j  = tau[bj];
    const float bias_j = bias[bj];
    float ow = 0.f, ob = 0.f;
    if (bj >= cN - cM) { ow = outw[bj - (cN - cM)]; ob = outb[bj - (cN - cM)]; }

    // A0 exchange: publish initial v (f32, agent scope), then arm slot gen 1.
#pragma unroll
    for (int r = 0; r < 4; ++r) {
        vold[r] = states[(size_t)(cb0 + r) * cN + bj];
        __hip_atomic_store(&v0[(size_t)(cb0 + r) * cN + bj], vold[r],
                           __ATOMIC_RELAXED, __HIP_MEMORY_SCOPE_AGENT);
    }
    if (tid == 0) { flagR = 0; flagS = 0; }
    __syncthreads();                       // vmcnt(0) drain: v0 stores complete
    if (tid == 0)
        __hip_atomic_store(mySlot, 1, __ATOMIC_RELAXED, __HIP_MEMORY_SCOPE_AGENT);

    // ---- uniformity probes over our column slice (only masked elems count) ----
    {
        bool badR = false, badS = false;
        const int jj = j0 + (tid & 15);
        const int i0 = (tid >> 4) * 32;
        for (int r = 0; r < 32; ++r) {
            size_t o = (size_t)(i0 + r) * cN + jj;
            if (mask[o]  != 0.f && (sigma[o]  != 0.5f || mu[o]  != 0.5f)) badR = true;
            if (smask[o] != 0.f && (ssigma[o] != 0.5f || smu[o] != 0.5f)) badS = true;
        }
        if (badR) flagR = 1;               // benign LDS race, same value
        if (badS) flagS = 1;
    }
    __syncthreads();
    const bool fastR = (flagR == 0), fastS = (flagS == 0);

    // ---- sensory reduction -> srb (s_rev + bias), swv (s_w) per owned cell ----
    float srb[4], swv[4];
    half8 bE[16], bW[16];                  // B-fragment regs; reused below
    if (fastS) {
        // sensory B fragments: B[k=s][n=j] = serev*smask | swgt*smask
#pragma unroll
        for (int kk = 0; kk < 16; ++kk) {
            half8 e8, w8;
#pragma unroll
            for (int t = 0; t < 8; ++t) {
                size_t o = (size_t)(kk * 32 + kbase + t) * cN + bj;
                float mk = smask[o];
                e8[t] = (_Float16)(serev[o] * mk);
                w8[t] = (_Float16)(swgt[o] * mk);
            }
            bE[kk] = e8; bW[kk] = w8;
        }
        floatx4 aR = {0.f, 0.f, 0.f, 0.f}, aW = {0.f, 0.f, 0.f, 0.f};
#pragma unroll
        for (int kk = 0; kk < 16; ++kk) {
            const float* xp = inputs + (size_t)arow * cS + kk * 32 + kbase;
            const float* wp = inw + kk * 32 + kbase;
            const float* bp = inb + kk * 32 + kbase;
            half8 ax;
#pragma unroll
            for (int t = 0; t < 8; ++t)
                ax[t] = (_Float16)clamp01(fmaf(xp[t], wp[t], bp[t]));
            aR = __builtin_amdgcn_mfma_f32_16x16x32_f16(ax, bE[kk], aR, 0, 0, 0);
            aW = __builtin_amdgcn_mfma_f32_16x16x32_f16(ax, bW[kk], aW, 0, 0, 0);
        }
#pragma unroll
        for (int r = 0; r < 4; ++r) { srb[r] = aR[r] + bias_j; swv[r] = aW[r]; }
    } else {
        // general sensory path (slow, correct)
        float sr4[4] = {0,0,0,0}, sw4[4] = {0,0,0,0};
        for (int s = 0; s < cS; ++s) {
            size_t o = (size_t)s * cN + bj;
            float mk = smask[o];
            float sg = ssigma[o];
            float a  = 0.5f / sg;
            float c  = fmaf(-smu[o], a, 0.5f);
            float ee = serev[o] * mk, ww = swgt[o] * mk;
            float iw = inw[s], ib = inb[s];
#pragma unroll
            for (int r = 0; r < 4; ++r) {
                float x = fmaf(inputs[(size_t)(cb0 + r) * cS + s], iw, ib);
                float g = clamp01(fmaf(x, a, c));
                sr4[r] = fmaf(g, ee, sr4[r]);
                sw4[r] = fmaf(g, ww, sw4[r]);
            }
        }
#pragma unroll
        for (int r = 0; r < 4; ++r) { srb[r] = sr4[r] + bias_j; swv[r] = sw4[r]; }
    }

    // ---- recurrent B fragments (held in regs for all 6 unfolds) ----
    if (fastR) {
#pragma unroll
        for (int kk = 0; kk < 16; ++kk) {
            half8 e8, w8;
#pragma unroll
            for (int t = 0; t < 8; ++t) {
                size_t o = (size_t)(kk * 32 + kbase + t) * cN + bj;
                float mk = mask[o];
                e8[t] = (_Float16)(erev[o] * mk);
                w8[t] = (_Float16)(wgt[o] * mk);
            }
            bE[kk] = e8; bW[kk] = w8;
        }
    }

    // ---- wait for all blocks' v0 (hidden behind the gathers above) ----
    if (tid < NBLK) {
        const int* sl = slots + tid * SLOT_STRIDE;
        while (__hip_atomic_load(sl, __ATOMIC_RELAXED, __HIP_MEMORY_SCOPE_AGENT) < 1)
            __builtin_amdgcn_s_sleep(1);
    }
    __syncthreads();

    // ---- 6 unfolds ----
    for (int u = 0; u < cUNF; ++u) {
        const float* vR = (u & 1) ? v1 : v0;
        float*       vW = (u & 1) ? v0 : v1;

        float sumE[4], sumW[4];
        if (fastR) {
            // A fragments: clamp01(v) cvt to f16, rows = this wave's M-tile.
            half8 ax[16];
#pragma unroll
            for (int kk = 0; kk < 16; ++kk) {
                union { unsigned long long u[4]; float f[8]; } cv;
                const unsigned long long* p = (const unsigned long long*)
                    (vR + (size_t)arow * cN + kk * 32 + kbase);
                cv.u[0] = __hip_atomic_load(p + 0, __ATOMIC_RELAXED, __HIP_MEMORY_SCOPE_AGENT);
                cv.u[1] = __hip_atomic_load(p + 1, __ATOMIC_RELAXED, __HIP_MEMORY_SCOPE_AGENT);
                cv.u[2] = __hip_atomic_load(p + 2, __ATOMIC_RELAXED, __HIP_MEMORY_SCOPE_AGENT);
                cv.u[3] = __hip_atomic_load(p + 3, __ATOMIC_RELAXED, __HIP_MEMORY_SCOPE_AGENT);
                half8 a8;
#pragma unroll
                for (int t = 0; t < 8; ++t)
                    a8[t] = (_Float16)clamp01(cv.f[t]);
                ax[kk] = a8;
            }
            floatx4 aE = {0.f, 0.f, 0.f, 0.f}, aWc = {0.f, 0.f, 0.f, 0.f};
#pragma unroll
            for (int kk = 0; kk < 16; ++kk) {
                aE  = __builtin_amdgcn_mfma_f32_16x16x32_f16(ax[kk], bE[kk], aE,  0, 0, 0);
                aWc = __builtin_amdgcn_mfma_f32_16x16x32_f16(ax[kk], bW[kk], aWc, 0, 0, 0);
            }
#pragma unroll
            for (int r = 0; r < 4; ++r) { sumE[r] = aE[r]; sumW[r] = aWc[r]; }
        } else {
            // general recurrent path (slow, correct): per-(i,j) gate
            float r4[4] = {0,0,0,0}, w4[4] = {0,0,0,0};
            for (int i = 0; i < cN; ++i) {
                size_t o = (size_t)i * cN + bj;
                float mk = mask[o];
                float sg = sigma[o];
                float a  = 0.5f / sg;
                float c  = fmaf(-mu[o], a, 0.5f);
                float ee = erev[o] * mk, ww = wgt[o] * mk;
#pragma unroll
                for (int r = 0; r < 4; ++r) {
                    float vi = __hip_atomic_load(&vR[(size_t)(cb0 + r) * cN + i],
                                                 __ATOMIC_RELAXED, __HIP_MEMORY_SCOPE_AGENT);
                    float g = clamp01(fmaf(vi, a, c));
                    r4[r] = fmaf(g, ee, r4[r]);
                    w4[r] = fmaf(g, ww, w4[r]);
                }
            }
#pragma unroll
            for (int r = 0; r < 4; ++r) { sumE[r] = r4[r]; sumW[r] = w4[r]; }
        }

        // v update for owned cells (all state in registers)
#pragma unroll
        for (int r = 0; r < 4; ++r) {
            float rr   = sumE[r] + srb[r];
            float wsum = sumW[r] + swv[r];
            float k    = 1.0f / (1.0f + wsum);
            float taun = tau_j * k;
            float inv  = 1.0f / (taun + cDELTA);
            float vn   = (taun * inv) * vold[r] + (cDELTA * inv) * k * rr;
            vold[r] = vn;
        }

        if (u < cUNF - 1) {
            // publish v(u+1) into the other buffer; generation barrier.
            // Ping-pong safety: a block reaching gen g+1 implies every block
            // stored slot>=g+1, which happens only after its reads of the
            // buffer we are about to overwrite (slot store follows the
            // __syncthreads that drains all memory ops).
#pragma unroll
            for (int r = 0; r < 4; ++r)
                __hip_atomic_store(&vW[(size_t)(cb0 + r) * cN + bj], vold[r],
                                   __ATOMIC_RELAXED, __HIP_MEMORY_SCOPE_AGENT);
            __syncthreads();               // vmcnt(0) drain of the v stores
            if (tid == 0)
                __hip_atomic_store(mySlot, u + 2,
                                   __ATOMIC_RELAXED, __HIP_MEMORY_SCOPE_AGENT);
            if (tid < NBLK) {
                const int* sl = slots + tid * SLOT_STRIDE;
                while (__hip_atomic_load(sl, __ATOMIC_RELAXED,
                                         __HIP_MEMORY_SCOPE_AGENT) < u + 2)
                    __builtin_amdgcn_s_sleep(1);
            }
            __syncthreads();
        }
    }

    // ---- epilogue: final v + mapped outputs ----
    float* vout = out + (size_t)cB * cM;
#pragma unroll
    for (int r = 0; r < 4; ++r) {
        int b = cb0 + r;
        vout[(size_t)b * cN + bj] = vold[r];
        if (bj >= cN - cM)
            out[(size_t)b * cM + (bj - (cN - cM))] = fmaf(vold[r], ow, ob);
    }
}

extern "C" void kernel_launch(void* const* d_in, const int* in_sizes, int n_in,
                              void* d_out, int out_size, void* d_ws, size_t ws_size,
                              hipStream_t stream)
{
    const float* inputs = (const float*)d_in[0];
    const float* states = (const float*)d_in[1];
    const float* tau    = (const float*)d_in[2];
    const float* bias   = (const float*)d_in[3];
    const float* erev   = (const float*)d_in[4];
    const float* wgt    = (const float*)d_in[5];
    const float* sigma  = (const float*)d_in[6];
    const float* mu     = (const float*)d_in[7];
    const float* serev  = (const float*)d_in[8];
    const float* swgt   = (const float*)d_in[9];
    const float* ssigma = (const float*)d_in[10];
    const float* smu    = (const float*)d_in[11];
    const float* mask   = (const float*)d_in[12];
    const float* smask  = (const float*)d_in[13];
    const float* inw    = (const float*)d_in[14];
    const float* inb    = (const float*)d_in[15];
    const float* outw   = (const float*)d_in[16];
    const float* outb   = (const float*)d_in[17];
    float* out = (float*)d_out;
    float* ws  = (float*)d_ws;

    // Single dispatch: 32 blocks x 256 threads, trivially co-resident on
    // 256 CUs -> internal generation-slot barriers cannot deadlock. Slot
    // generations start from harness poison (negative as int); no memset.
    k_fused<<<NBLK, NT, 0, stream>>>(inputs, states, tau, bias, erev, wgt,
                                     sigma, mu, serev, swgt, ssigma, smu,
                                     mask, smask, inw, inb, outw, outb,
                                     out, ws);
}

// Round 2
// 160.789 us; speedup vs baseline: 1.4967x; 1.4967x over previous
//
#include <hip/hip_runtime.h>
#include <string.h>

// Problem constants
constexpr int cB = 64, cS = 512, cN = 512, cM = 128, cUNF = 6;
constexpr float cDELTA = 0.016666666666666666f;  // DT/UNFOLDS = 0.1/6

// r17: r16's fused MFMA design, with the data movement repaired.
//   r16 post-mortem: k_fused ran 180-207us, VALUBusy 0.5%, FETCH 14.3MB at
//   75 GB/s, VGPR_Count=128 (vs ~230 requested -> compiler spilled /
//   rematerialized the fragment gathers). The 4B stride-2KB gathers on 32
//   CUs at 1.5% occupancy were pure latency serialization.
//   Fixes:
//   - k_pack (256 blocks x 256 thr): full-occupancy read of all weight/mask/
//     probe arrays; writes a 2MB f16 fragment-layout table (16B per half8
//     fragment, fully coalesced) + per-j-tile uniformity flags.
//   - k_fused (32 blocks x 256 thr): copies its 64KB packed slice into LDS
//     once (coalesced 16B loads); MFMA B-operands come from ds_read_b128
//     (per-step wave read = contiguous 1KB, conflict-free). B-fragments were
//     4x-redundant across the block's waves in registers anyway.
//   - unfold 0 reads `states` directly: initial publish + barrier removed
//     (5 generation barriers, gens 1..5; harness poison is negative as int).
constexpr int JT   = 16;            // j-columns per block
constexpr int NBLK = cN / JT;       // 32 blocks
constexpr int NT   = 256;           // 4 waves; wave = M-tile (16 batches)
constexpr int SLOT_STRIDE = 16;     // ints; 64 B slot spacing

// ws layout (float offsets)
constexpr size_t OFF_V0   = 0;                          // [B][N] f32 ping
constexpr size_t OFF_V1   = (size_t)cB * cN;            // [B][N] f32 pong
constexpr size_t OFF_SLOT = OFF_V1 + (size_t)cB * cN;   // 32 slots x 16 ints
constexpr size_t OFF_FLAG = OFF_SLOT + 1024;            // 64 ints (R:0..31, S:32..63)
constexpr size_t OFF_PKR  = 131072;                     // packed recurrent, 1 MB
constexpr size_t OFF_PKS  = OFF_PKR + 262144;           // packed sensory, 1 MB
// packed table layout (uint4 index, per table):
//   [jt][mat][kk][lg][lr] -> jt*2048 + mat*1024 + kk*64 + lg*16 + lr
// so a wave's fragment read for one (mat,kk) step is a contiguous 1 KB.

typedef _Float16 half8 __attribute__((ext_vector_type(8)));
typedef float    floatx4 __attribute__((ext_vector_type(4)));

__device__ __forceinline__ float clamp01(float x) {
    return __builtin_amdgcn_fmed3f(x, 0.0f, 1.0f);
}

// ---- k_pack: full-occupancy fragment pack + uniformity probe ----
__global__ __launch_bounds__(NT)
void k_pack(const float* __restrict__ erev,   const float* __restrict__ wgt,
            const float* __restrict__ sigma,  const float* __restrict__ mu,
            const float* __restrict__ serev,  const float* __restrict__ swgt,
            const float* __restrict__ ssigma, const float* __restrict__ smu,
            const float* __restrict__ mask,   const float* __restrict__ smask,
            float* __restrict__ ws)
{
    const int g = blockIdx.x * NT + threadIdx.x;   // 65536 threads
    const int e = g & 32767;                       // fragment id
    const int lr = e & 15, lg = (e >> 4) & 3, kk = (e >> 6) & 15, jt = e >> 10;
    const int j  = jt * JT + lr;
    const int k0 = kk * 32 + lg * 8;
    const bool sens = (g >= 32768);

    const float* E  = sens ? serev  : erev;
    const float* W  = sens ? swgt   : wgt;
    const float* SG = sens ? ssigma : sigma;
    const float* MU = sens ? smu    : mu;
    const float* MK = sens ? smask  : mask;

    half8 e8, w8;
    bool bad = false;
#pragma unroll
    for (int t = 0; t < 8; ++t) {
        size_t o = (size_t)(k0 + t) * cN + j;
        float mk = MK[o];
        e8[t] = (_Float16)(E[o] * mk);
        w8[t] = (_Float16)(W[o] * mk);
        if (mk != 0.0f && (SG[o] != 0.5f || MU[o] != 0.5f)) bad = true;
    }

    uint4* dst = (uint4*)(ws + (sens ? OFF_PKS : OFF_PKR));
    size_t di = (size_t)jt * 2048 + (size_t)kk * 64 + lg * 16 + lr;
    dst[di]        = *(uint4*)&e8;     // mat 0: erev*mask
    dst[di + 1024] = *(uint4*)&w8;     // mat 1: w*mask

    int* flags = (int*)(ws + OFF_FLAG);
    if (bad)
        __hip_atomic_store(&flags[(sens ? NBLK : 0) + jt], 1,
                           __ATOMIC_RELAXED, __HIP_MEMORY_SCOPE_AGENT);
}

// ---- k_fused: LDS-resident B fragments + MFMA unfolds + slot barrier ----
__global__ __launch_bounds__(NT, 1)
void k_fused(const float* __restrict__ inputs, const float* __restrict__ states,
             const float* __restrict__ tau,    const float* __restrict__ bias,
             const float* __restrict__ erev,   const float* __restrict__ wgt,
             const float* __restrict__ sigma,  const float* __restrict__ mu,
             const float* __restrict__ serev,  const float* __restrict__ swgt,
             const float* __restrict__ ssigma, const float* __restrict__ smu,
             const float* __restrict__ mask,   const float* __restrict__ smask,
             const float* __restrict__ inw,    const float* __restrict__ inb,
             const float* __restrict__ outw,   const float* __restrict__ outb,
             float* __restrict__ out, float* __restrict__ ws)
{
    float* v0 = ws + OFF_V0;
    float* v1 = ws + OFF_V1;
    int* slots = (int*)(ws + OFF_SLOT);

    const int tid  = threadIdx.x;
    const int blk  = blockIdx.x;
    const int j0   = blk * JT;
    const int lane = tid & 63;
    const int mt   = tid >> 6;          // wave id == M-tile (batch group of 16)
    const int lr   = lane & 15;         // row/col index within 16x16 tile
    const int lg   = lane >> 4;         // k-group (A/B), row-group (C/D)
    const int bj   = j0 + lr;           // this lane's output column j (B/C)
    const int arow = mt * 16 + lr;      // this lane's A-fragment row (batch)
    const int kbase = lg * 8;           // k offset inside a K=32 step
    const int cb0  = mt * 16 + lg * 4;  // first owned batch row (C mapping)

    int* mySlot = slots + blk * SLOT_STRIDE;

    __shared__ uint4 lds[4096];         // 64 KB: [0,2048)=recurrent, [2048,4096)=sensory
    const half8* hR = (const half8*)lds;        // E at kk*64+lane, W at +1024
    const half8* hS = (const half8*)lds + 2048;

    // ---- per-lane owned cells: (b = cb0+r, j = bj), r = 0..3 ----
    float vold[4];
#pragma unroll
    for (int r = 0; r < 4; ++r)
        vold[r] = states[(size_t)(cb0 + r) * cN + bj];
    const float tau_j  = tau[bj];
    const float bias_j = bias[bj];
    float ow = 0.f, ob = 0.f;
    if (bj >= cN - cM) { ow = outw[bj - (cN - cM)]; ob = outb[bj - (cN - cM)]; }

    // ---- LDS fill: 64 KB packed slice, coalesced 16B loads ----
    const uint4* gR = (const uint4*)(ws + OFF_PKR) + (size_t)blk * 2048;
    const uint4* gS = (const uint4*)(ws + OFF_PKS) + (size_t)blk * 2048;
#pragma unroll
    for (int r = 0; r < 8; ++r) lds[r * NT + tid]        = gR[r * NT + tid];
#pragma unroll
    for (int r = 0; r < 8; ++r) lds[2048 + r * NT + tid] = gS[r * NT + tid];

    const int* flags = (const int*)(ws + OFF_FLAG);
    const bool fastR = (flags[blk] != 1);        // poison != 1 -> uniform
    const bool fastS = (flags[NBLK + blk] != 1);
    __syncthreads();

    // ---- sensory reduction -> srb (s_rev + bias), swv (s_w) ----
    float srb[4], swv[4];
    if (fastS) {
        floatx4 aR = {0.f, 0.f, 0.f, 0.f}, aW = {0.f, 0.f, 0.f, 0.f};
#pragma unroll
        for (int kk = 0; kk < 16; ++kk) {
            const float* xp = inputs + (size_t)arow * cS + kk * 32 + kbase;
            const float* wp = inw + kk * 32 + kbase;
            const float* bp = inb + kk * 32 + kbase;
            half8 ax;
#pragma unroll
            for (int t = 0; t < 8; ++t)
                ax[t] = (_Float16)clamp01(fmaf(xp[t], wp[t], bp[t]));
            half8 be = hS[kk * 64 + lane];
            half8 bw = hS[1024 + kk * 64 + lane];
            aR = __builtin_amdgcn_mfma_f32_16x16x32_f16(ax, be, aR, 0, 0, 0);
            aW = __builtin_amdgcn_mfma_f32_16x16x32_f16(ax, bw, aW, 0, 0, 0);
        }
#pragma unroll
        for (int r = 0; r < 4; ++r) { srb[r] = aR[r] + bias_j; swv[r] = aW[r]; }
    } else {
        // general sensory path (slow, correct, unexercised by the bench)
        float sr4[4] = {0,0,0,0}, sw4[4] = {0,0,0,0};
        for (int s = 0; s < cS; ++s) {
            size_t o = (size_t)s * cN + bj;
            float mk = smask[o];
            float sg = ssigma[o];
            float a  = 0.5f / sg;
            float c  = fmaf(-smu[o], a, 0.5f);
            float ee = serev[o] * mk, ww = swgt[o] * mk;
            float iw = inw[s], ib = inb[s];
#pragma unroll
            for (int r = 0; r < 4; ++r) {
                float x = fmaf(inputs[(size_t)(cb0 + r) * cS + s], iw, ib);
                float g = clamp01(fmaf(x, a, c));
                sr4[r] = fmaf(g, ee, sr4[r]);
                sw4[r] = fmaf(g, ww, sw4[r]);
            }
        }
#pragma unroll
        for (int r = 0; r < 4; ++r) { srb[r] = sr4[r] + bias_j; swv[r] = sw4[r]; }
    }

    // ---- 6 unfolds; unfold 0 reads `states` directly (no init barrier) ----
    for (int u = 0; u < cUNF; ++u) {
        const float* vRp = (u == 0) ? states : ((u & 1) ? v0 : v1);
        float*       vWp = (u & 1) ? v1 : v0;

        float sumE[4], sumW[4];
        if (fastR) {
            // A fragments: clamp01(v) -> f16; rows = this wave's M-tile.
            half8 ax[16];
            const float* vrow = vRp + (size_t)arow * cN;
#pragma unroll
            for (int kk = 0; kk < 16; ++kk) {
                union { unsigned long long u[4]; float f[8]; } cv;
                const unsigned long long* p =
                    (const unsigned long long*)(vrow + kk * 32 + kbase);
                cv.u[0] = __hip_atomic_load(p + 0, __ATOMIC_RELAXED, __HIP_MEMORY_SCOPE_AGENT);
                cv.u[1] = __hip_atomic_load(p + 1, __ATOMIC_RELAXED, __HIP_MEMORY_SCOPE_AGENT);
                cv.u[2] = __hip_atomic_load(p + 2, __ATOMIC_RELAXED, __HIP_MEMORY_SCOPE_AGENT);
                cv.u[3] = __hip_atomic_load(p + 3, __ATOMIC_RELAXED, __HIP_MEMORY_SCOPE_AGENT);
                half8 a8;
#pragma unroll
                for (int t = 0; t < 8; ++t)
                    a8[t] = (_Float16)clamp01(cv.f[t]);
                ax[kk] = a8;
            }
            floatx4 aE = {0.f, 0.f, 0.f, 0.f}, aWc = {0.f, 0.f, 0.f, 0.f};
#pragma unroll
            for (int kk = 0; kk < 16; ++kk) {
                half8 be = hR[kk * 64 + lane];
                half8 bw = hR[1024 + kk * 64 + lane];
                aE  = __builtin_amdgcn_mfma_f32_16x16x32_f16(ax[kk], be, aE,  0, 0, 0);
                aWc = __builtin_amdgcn_mfma_f32_16x16x32_f16(ax[kk], bw, aWc, 0, 0, 0);
            }
#pragma unroll
            for (int r = 0; r < 4; ++r) { sumE[r] = aE[r]; sumW[r] = aWc[r]; }
        } else {
            // general recurrent path (slow, correct)
            float r4[4] = {0,0,0,0}, w4[4] = {0,0,0,0};
            for (int i = 0; i < cN; ++i) {
                size_t o = (size_t)i * cN + bj;
                float mk = mask[o];
                float sg = sigma[o];
                float a  = 0.5f / sg;
                float c  = fmaf(-mu[o], a, 0.5f);
                float ee = erev[o] * mk, ww = wgt[o] * mk;
#pragma unroll
                for (int r = 0; r < 4; ++r) {
                    float vi = __hip_atomic_load(&vRp[(size_t)(cb0 + r) * cN + i],
                                                 __ATOMIC_RELAXED, __HIP_MEMORY_SCOPE_AGENT);
                    float g = clamp01(fmaf(vi, a, c));
                    r4[r] = fmaf(g, ee, r4[r]);
                    w4[r] = fmaf(g, ww, w4[r]);
                }
            }
#pragma unroll
            for (int r = 0; r < 4; ++r) { sumE[r] = r4[r]; sumW[r] = w4[r]; }
        }

        // v update for owned cells (all state in registers)
#pragma unroll
        for (int r = 0; r < 4; ++r) {
            float rr   = sumE[r] + srb[r];
            float wsum = sumW[r] + swv[r];
            float k    = 1.0f / (1.0f + wsum);
            float taun = tau_j * k;
            float inv  = 1.0f / (taun + cDELTA);
            float vn   = (taun * inv) * vold[r] + (cDELTA * inv) * k * rr;
            vold[r] = vn;
        }

        if (u < cUNF - 1) {
            // publish v(u+1); generation barrier gen u+1 (1..5).
            // Safety: slot store follows a __syncthreads that drains all
            // prior memory ops (incl. this block's READS of vRp), so a block
            // observing all slots >= u+1 may overwrite vRp's buffer.
#pragma unroll
            for (int r = 0; r < 4; ++r)
                __hip_atomic_store(&vWp[(size_t)(cb0 + r) * cN + bj], vold[r],
                                   __ATOMIC_RELAXED, __HIP_MEMORY_SCOPE_AGENT);
            __syncthreads();               // vmcnt(0) drain of the v stores
            if (tid == 0)
                __hip_atomic_store(mySlot, u + 1,
                                   __ATOMIC_RELAXED, __HIP_MEMORY_SCOPE_AGENT);
            if (tid < NBLK) {
                const int* sl = slots + tid * SLOT_STRIDE;
                while (__hip_atomic_load(sl, __ATOMIC_RELAXED,
                                         __HIP_MEMORY_SCOPE_AGENT) < u + 1)
                    __builtin_amdgcn_s_sleep(1);
            }
            __syncthreads();
        }
    }

    // ---- epilogue: final v + mapped outputs ----
    float* vout = out + (size_t)cB * cM;
#pragma unroll
    for (int r = 0; r < 4; ++r) {
        int b = cb0 + r;
        vout[(size_t)b * cN + bj] = vold[r];
        if (bj >= cN - cM)
            out[(size_t)b * cM + (bj - (cN - cM))] = fmaf(vold[r], ow, ob);
    }
}

extern "C" void kernel_launch(void* const* d_in, const int* in_sizes, int n_in,
                              void* d_out, int out_size, void* d_ws, size_t ws_size,
                              hipStream_t stream)
{
    const float* inputs = (const float*)d_in[0];
    const float* states = (const float*)d_in[1];
    const float* tau    = (const float*)d_in[2];
    const float* bias   = (const float*)d_in[3];
    const float* erev   = (const float*)d_in[4];
    const float* wgt    = (const float*)d_in[5];
    const float* sigma  = (const float*)d_in[6];
    const float* mu     = (const float*)d_in[7];
    const float* serev  = (const float*)d_in[8];
    const float* swgt   = (const float*)d_in[9];
    const float* ssigma = (const float*)d_in[10];
    const float* smu    = (const float*)d_in[11];
    const float* mask   = (const float*)d_in[12];
    const float* smask  = (const float*)d_in[13];
    const float* inw    = (const float*)d_in[14];
    const float* inb    = (const float*)d_in[15];
    const float* outw   = (const float*)d_in[16];
    const float* outb   = (const float*)d_in[17];
    float* out = (float*)d_out;
    float* ws  = (float*)d_ws;

    // k_pack: 256 blocks x 256 thr (full occupancy) packs the 2MB f16
    // fragment table + flags. k_fused: 32 blocks x 256 thr, trivially
    // co-resident -> internal generation-slot barriers cannot deadlock.
    // Slot generations start from harness poison (negative as int).
    k_pack<<<NT, NT, 0, stream>>>(erev, wgt, sigma, mu, serev, swgt,
                                  ssigma, smu, mask, smask, ws);
    k_fused<<<NBLK, NT, 0, stream>>>(inputs, states, tau, bias, erev, wgt,
                                     sigma, mu, serev, swgt, ssigma, smu,
                                     mask, smask, inw, inb, outw, outb,
                                     out, ws);
}

// Round 3
// 147.378 us; speedup vs baseline: 1.6328x; 1.0910x over previous
//
#include <hip/hip_runtime.h>
#include <string.h>

// Problem constants
constexpr int cB = 64, cS = 512, cN = 512, cM = 128, cUNF = 6;
constexpr float cDELTA = 0.016666666666666666f;  // DT/UNFOLDS = 0.1/6

// r18: single-kernel fused MFMA design.
//   r17 post-mortem: k_fused 59.5us with VALUBusy 0.75% (99% stall); k_pack +
//   two dispatch gaps/flushes ate the other ~60us. Fixes:
//   - ONE kernel: each block gathers its own 16-column weight slice straight
//     from the source arrays (read-only -> plain cached loads, pipelined)
//     into a 64KB LDS f16 fragment table; uniformity probe fused in.
//   - Unfold A-gather: 32x global_load_dwordx4 sc0 sc1 issued via asm with
//     immediate offsets + ONE s_waitcnt vmcnt(0) + sched_barrier(0)
//     (rule #18) -- one L3 round trip instead of 64 serialized atomic loads.
//   - 32 blocks x 256 thr; generation-slot barrier unchanged (harness poison
//     is negative as int; gens 1..5; no initialization).
constexpr int JT   = 16;            // j-columns per block
constexpr int NBLK = cN / JT;       // 32 blocks
constexpr int NT   = 256;           // 4 waves; wave = M-tile (16 batches)
constexpr int SLOT_STRIDE = 16;     // ints; 64 B slot spacing

// ws layout (float offsets)
constexpr size_t OFF_V0   = 0;                          // [B][N] f32 ping
constexpr size_t OFF_V1   = (size_t)cB * cN;            // [B][N] f32 pong
constexpr size_t OFF_SLOT = OFF_V1 + (size_t)cB * cN;   // 32 slots x 16 ints

typedef _Float16 half8 __attribute__((ext_vector_type(8)));
typedef float    floatx4 __attribute__((ext_vector_type(4)));

__device__ __forceinline__ float clamp01(float x) {
    return __builtin_amdgcn_fmed3f(x, 0.0f, 1.0f);
}

// Gather one [512 x 16] weight-pair slice into LDS fragment layout (f16),
// fusing the sigma/mu uniformity probe. H[0..8191] = E*mask halves,
// H[8192..16383] = W*mask halves; frag f = kk*64 + lg*16 + lr, elem t:
// half index f*8 + t, with i = kk*32 + lg*8 + t, j = j0 + lr.
__device__ __forceinline__ void gather_slice(
    const float* __restrict__ E,  const float* __restrict__ W,
    const float* __restrict__ SG, const float* __restrict__ MU,
    const float* __restrict__ MK,
    int j0, int tid, _Float16* H, int* badFlag)
{
    const int q = tid & 3, r0 = tid >> 2;   // q: 16B column quarter, r0: row
    bool bad = false;
#pragma unroll
    for (int p = 0; p < 8; ++p) {
        const int i = p * 64 + r0;
        const size_t o = (size_t)i * cN + j0 + q * 4;
        const float4 e4  = *(const float4*)(E + o);
        const float4 w4  = *(const float4*)(W + o);
        const float4 m4  = *(const float4*)(MK + o);
        const float4 sg4 = *(const float4*)(SG + o);
        const float4 mu4 = *(const float4*)(MU + o);
        if ((m4.x != 0.f && (sg4.x != 0.5f || mu4.x != 0.5f)) ||
            (m4.y != 0.f && (sg4.y != 0.5f || mu4.y != 0.5f)) ||
            (m4.z != 0.f && (sg4.z != 0.5f || mu4.z != 0.5f)) ||
            (m4.w != 0.f && (sg4.w != 0.5f || mu4.w != 0.5f))) bad = true;
        const int base = (((i >> 5) * 64) + (((i >> 3) & 3) * 16) + q * 4) * 8
                         + (i & 7);
        H[base +  0] = (_Float16)(e4.x * m4.x);
        H[base +  8] = (_Float16)(e4.y * m4.y);
        H[base + 16] = (_Float16)(e4.z * m4.z);
        H[base + 24] = (_Float16)(e4.w * m4.w);
        H[8192 + base +  0] = (_Float16)(w4.x * m4.x);
        H[8192 + base +  8] = (_Float16)(w4.y * m4.y);
        H[8192 + base + 16] = (_Float16)(w4.z * m4.z);
        H[8192 + base + 24] = (_Float16)(w4.w * m4.w);
    }
    if (bad) *badFlag = 1;   // benign LDS race (same value)
}

__global__ __launch_bounds__(NT, 1)
void k_fused(const float* __restrict__ inputs, const float* __restrict__ states,
             const float* __restrict__ tau,    const float* __restrict__ bias,
             const float* __restrict__ erev,   const float* __restrict__ wgt,
             const float* __restrict__ sigma,  const float* __restrict__ mu,
             const float* __restrict__ serev,  const float* __restrict__ swgt,
             const float* __restrict__ ssigma, const float* __restrict__ smu,
             const float* __restrict__ mask,   const float* __restrict__ smask,
             const float* __restrict__ inw,    const float* __restrict__ inb,
             const float* __restrict__ outw,   const float* __restrict__ outb,
             float* __restrict__ out, float* __restrict__ ws)
{
    float* v0 = ws + OFF_V0;
    float* v1 = ws + OFF_V1;
    int* slots = (int*)(ws + OFF_SLOT);

    const int tid  = threadIdx.x;
    const int blk  = blockIdx.x;
    const int j0   = blk * JT;
    const int lane = tid & 63;
    const int mt   = tid >> 6;          // wave id == M-tile (batch group of 16)
    const int lr   = lane & 15;         // row/col index within 16x16 tile
    const int lg   = lane >> 4;         // k-group (A/B), row-group (C/D)
    const int bj   = j0 + lr;           // this lane's output column j (B/C)
    const int arow = mt * 16 + lr;      // this lane's A-fragment row (batch)
    const int kbase = lg * 8;           // k offset inside a K=32 step
    const int cb0  = mt * 16 + lg * 4;  // first owned batch row (C mapping)

    int* mySlot = slots + blk * SLOT_STRIDE;

    // 64 KB LDS fragment table:
    //   halves [0,8192)      recurrent E*mask   [8192,16384)  recurrent W*mask
    //   halves [16384,24576) sensory  E*mask    [24576,32768) sensory  W*mask
    __shared__ _Float16 Hlds[32768];
    __shared__ int sBad[2];             // [0]=recurrent, [1]=sensory
    const half8* hfr = (const half8*)Hlds;

    if (tid < 2) sBad[tid] = 0;
    __syncthreads();                    // init visible before probe writes

    // ---- per-lane owned cells: (b = cb0+r, j = bj), r = 0..3 ----
    float vold[4];
#pragma unroll
    for (int r = 0; r < 4; ++r)
        vold[r] = states[(size_t)(cb0 + r) * cN + bj];
    const float tau_j  = tau[bj];
    const float bias_j = bias[bj];
    float ow = 0.f, ob = 0.f;
    if (bj >= cN - cM) { ow = outw[bj - (cN - cM)]; ob = outb[bj - (cN - cM)]; }

    // ---- gather both weight slices (plain cached loads; read-only arrays) ----
    gather_slice(erev,  wgt,  sigma,  mu,  mask,  j0, tid, Hlds,         &sBad[0]);
    gather_slice(serev, swgt, ssigma, smu, smask, j0, tid, Hlds + 16384, &sBad[1]);
    __syncthreads();
    const bool fastR = (sBad[0] == 0);
    const bool fastS = (sBad[1] == 0);

    // ---- sensory reduction -> srb (s_rev + bias), swv (s_w) ----
    float srb[4], swv[4];
    if (fastS) {
        floatx4 aR = {0.f, 0.f, 0.f, 0.f}, aW = {0.f, 0.f, 0.f, 0.f};
#pragma unroll
        for (int kk = 0; kk < 16; ++kk) {
            const int off = kk * 32 + kbase;
            const float4 xa = *(const float4*)(inputs + (size_t)arow * cS + off);
            const float4 xb = *(const float4*)(inputs + (size_t)arow * cS + off + 4);
            const float4 wa = *(const float4*)(inw + off);
            const float4 wb = *(const float4*)(inw + off + 4);
            const float4 ba = *(const float4*)(inb + off);
            const float4 bb = *(const float4*)(inb + off + 4);
            half8 ax;
            ax[0] = (_Float16)clamp01(fmaf(xa.x, wa.x, ba.x));
            ax[1] = (_Float16)clamp01(fmaf(xa.y, wa.y, ba.y));
            ax[2] = (_Float16)clamp01(fmaf(xa.z, wa.z, ba.z));
            ax[3] = (_Float16)clamp01(fmaf(xa.w, wa.w, ba.w));
            ax[4] = (_Float16)clamp01(fmaf(xb.x, wb.x, bb.x));
            ax[5] = (_Float16)clamp01(fmaf(xb.y, wb.y, bb.y));
            ax[6] = (_Float16)clamp01(fmaf(xb.z, wb.z, bb.z));
            ax[7] = (_Float16)clamp01(fmaf(xb.w, wb.w, bb.w));
            aR = __builtin_amdgcn_mfma_f32_16x16x32_f16(ax, hfr[2048 + kk * 64 + lane], aR, 0, 0, 0);
            aW = __builtin_amdgcn_mfma_f32_16x16x32_f16(ax, hfr[3072 + kk * 64 + lane], aW, 0, 0, 0);
        }
#pragma unroll
        for (int r = 0; r < 4; ++r) { srb[r] = aR[r] + bias_j; swv[r] = aW[r]; }
    } else {
        // general sensory path (slow, correct, unexercised by the bench)
        float sr4[4] = {0,0,0,0}, sw4[4] = {0,0,0,0};
        for (int s = 0; s < cS; ++s) {
            size_t o = (size_t)s * cN + bj;
            float mk = smask[o];
            float sg = ssigma[o];
            float a  = 0.5f / sg;
            float c  = fmaf(-smu[o], a, 0.5f);
            float ee = serev[o] * mk, ww = swgt[o] * mk;
            float iw = inw[s], ib = inb[s];
#pragma unroll
            for (int r = 0; r < 4; ++r) {
                float x = fmaf(inputs[(size_t)(cb0 + r) * cS + s], iw, ib);
                float g = clamp01(fmaf(x, a, c));
                sr4[r] = fmaf(g, ee, sr4[r]);
                sw4[r] = fmaf(g, ww, sw4[r]);
            }
        }
#pragma unroll
        for (int r = 0; r < 4; ++r) { srb[r] = sr4[r] + bias_j; swv[r] = sw4[r]; }
    }

    // ---- 6 unfolds; unfold 0 reads `states` directly ----
    for (int u = 0; u < cUNF; ++u) {
        const float* vRp = (u == 0) ? states : ((u & 1) ? v0 : v1);
        float*       vWp = (u & 1) ? v1 : v0;

        float sumE[4], sumW[4];
        if (fastR) {
            // A-gather: 32 pipelined dwordx4 sc0 sc1 loads, ONE waitcnt.
            floatx4 cv0[16], cv1[16];
            const float* vrow = vRp + (size_t)arow * cN + kbase;
#pragma unroll
            for (int kk = 0; kk < 16; ++kk) {
                asm volatile("global_load_dwordx4 %0, %1, off offset:%2 sc0 sc1"
                             : "=v"(cv0[kk]) : "v"(vrow), "n"(kk * 128) : "memory");
                asm volatile("global_load_dwordx4 %0, %1, off offset:%2 sc0 sc1"
                             : "=v"(cv1[kk]) : "v"(vrow), "n"(kk * 128 + 16) : "memory");
            }
            asm volatile("s_waitcnt vmcnt(0)" ::: "memory");
            __builtin_amdgcn_sched_barrier(0);   // rule #18: pin consumers below

            floatx4 aE = {0.f, 0.f, 0.f, 0.f}, aWc = {0.f, 0.f, 0.f, 0.f};
#pragma unroll
            for (int kk = 0; kk < 16; ++kk) {
                half8 a8;
                a8[0] = (_Float16)clamp01(cv0[kk][0]);
                a8[1] = (_Float16)clamp01(cv0[kk][1]);
                a8[2] = (_Float16)clamp01(cv0[kk][2]);
                a8[3] = (_Float16)clamp01(cv0[kk][3]);
                a8[4] = (_Float16)clamp01(cv1[kk][0]);
                a8[5] = (_Float16)clamp01(cv1[kk][1]);
                a8[6] = (_Float16)clamp01(cv1[kk][2]);
                a8[7] = (_Float16)clamp01(cv1[kk][3]);
                aE  = __builtin_amdgcn_mfma_f32_16x16x32_f16(a8, hfr[kk * 64 + lane], aE,  0, 0, 0);
                aWc = __builtin_amdgcn_mfma_f32_16x16x32_f16(a8, hfr[1024 + kk * 64 + lane], aWc, 0, 0, 0);
            }
#pragma unroll
            for (int r = 0; r < 4; ++r) { sumE[r] = aE[r]; sumW[r] = aWc[r]; }
        } else {
            // general recurrent path (slow, correct)
            float r4[4] = {0,0,0,0}, w4[4] = {0,0,0,0};
            for (int i = 0; i < cN; ++i) {
                size_t o = (size_t)i * cN + bj;
                float mk = mask[o];
                float sg = sigma[o];
                float a  = 0.5f / sg;
                float c  = fmaf(-mu[o], a, 0.5f);
                float ee = erev[o] * mk, ww = wgt[o] * mk;
#pragma unroll
                for (int r = 0; r < 4; ++r) {
                    float vi = __hip_atomic_load(&vRp[(size_t)(cb0 + r) * cN + i],
                                                 __ATOMIC_RELAXED, __HIP_MEMORY_SCOPE_AGENT);
                    float g = clamp01(fmaf(vi, a, c));
                    r4[r] = fmaf(g, ee, r4[r]);
                    w4[r] = fmaf(g, ww, w4[r]);
                }
            }
#pragma unroll
            for (int r = 0; r < 4; ++r) { sumE[r] = r4[r]; sumW[r] = w4[r]; }
        }

        // v update for owned cells (all state in registers)
#pragma unroll
        for (int r = 0; r < 4; ++r) {
            float rr   = sumE[r] + srb[r];
            float wsum = sumW[r] + swv[r];
            float k    = 1.0f / (1.0f + wsum);
            float taun = tau_j * k;
            float inv  = 1.0f / (taun + cDELTA);
            float vn   = (taun * inv) * vold[r] + (cDELTA * inv) * k * rr;
            vold[r] = vn;
        }

        if (u < cUNF - 1) {
            // publish v(u+1); generation barrier gen u+1 (1..5).
            // Safety: slot store follows a __syncthreads that drains all prior
            // memory ops (incl. this block's reads of vRp), so a block
            // observing all slots >= u+1 may overwrite vRp's buffer.
#pragma unroll
            for (int r = 0; r < 4; ++r)
                __hip_atomic_store(&vWp[(size_t)(cb0 + r) * cN + bj], vold[r],
                                   __ATOMIC_RELAXED, __HIP_MEMORY_SCOPE_AGENT);
            __syncthreads();               // vmcnt(0) drain of the v stores
            if (tid == 0)
                __hip_atomic_store(mySlot, u + 1,
                                   __ATOMIC_RELAXED, __HIP_MEMORY_SCOPE_AGENT);
            if (tid < NBLK) {
                const int* sl = slots + tid * SLOT_STRIDE;
                while (__hip_atomic_load(sl, __ATOMIC_RELAXED,
                                         __HIP_MEMORY_SCOPE_AGENT) < u + 1)
                    __builtin_amdgcn_s_sleep(1);
            }
            __syncthreads();
        }
    }

    // ---- epilogue: final v + mapped outputs ----
    float* vout = out + (size_t)cB * cM;
#pragma unroll
    for (int r = 0; r < 4; ++r) {
        int b = cb0 + r;
        vout[(size_t)b * cN + bj] = vold[r];
        if (bj >= cN - cM)
            out[(size_t)b * cM + (bj - (cN - cM))] = fmaf(vold[r], ow, ob);
    }
}

extern "C" void kernel_launch(void* const* d_in, const int* in_sizes, int n_in,
                              void* d_out, int out_size, void* d_ws, size_t ws_size,
                              hipStream_t stream)
{
    const float* inputs = (const float*)d_in[0];
    const float* states = (const float*)d_in[1];
    const float* tau    = (const float*)d_in[2];
    const float* bias   = (const float*)d_in[3];
    const float* erev   = (const float*)d_in[4];
    const float* wgt    = (const float*)d_in[5];
    const float* sigma  = (const float*)d_in[6];
    const float* mu     = (const float*)d_in[7];
    const float* serev  = (const float*)d_in[8];
    const float* swgt   = (const float*)d_in[9];
    const float* ssigma = (const float*)d_in[10];
    const float* smu    = (const float*)d_in[11];
    const float* mask   = (const float*)d_in[12];
    const float* smask  = (const float*)d_in[13];
    const float* inw    = (const float*)d_in[14];
    const float* inb    = (const float*)d_in[15];
    const float* outw   = (const float*)d_in[16];
    const float* outb   = (const float*)d_in[17];
    float* out = (float*)d_out;
    float* ws  = (float*)d_ws;

    // Single dispatch: 32 blocks x 256 threads, trivially co-resident on
    // 256 CUs -> internal generation-slot barriers cannot deadlock. Slot
    // generations start from harness poison (negative as int); no memset.
    k_fused<<<NBLK, NT, 0, stream>>>(inputs, states, tau, bias, erev, wgt,
                                     sigma, mu, serev, swgt, ssigma, smu,
                                     mask, smask, inw, inb, outw, outb,
                                     out, ws);
}

// Round 4
// 133.443 us; speedup vs baseline: 1.8034x; 1.1044x over previous
//
#include <hip/hip_runtime.h>
#include <string.h>

// Problem constants
constexpr int cB = 64, cS = 512, cN = 512, cM = 128, cUNF = 6;
constexpr float cDELTA = 0.016666666666666666f;  // DT/UNFOLDS = 0.1/6

// r19: r18 single-kernel fused MFMA design, gather-parallelism + f16 exchange.
//   r18 post-mortem: k_fused 66us, FETCH 14MB @ 228 GB/s, VALUBusy 0.87%.
//   The weight-gather prologue (11MB cold HBM) ran on 32 CUs x 1 wave/SIMD
//   -> latency-bound at ~1/30 of achievable BW (~48us of the 66). The u>=1
//   A-gather kept 32 floatx4 asm results live (128 VGPR > 116 alloc).
//   Fixes:
//   - NT=1024 (16 waves, 4/SIMD): 4x gather parallelism; waves 4..15 idle
//     at barriers during unfolds (harmless).
//   - f16 gated-v exchange: owners publish (_Float16)clamp01(v) (bit-equal
//     to what readers computed in r18) via global_store_short sc0 sc1 into
//     ping/pong h-buffers; fast readers load 16x16B half8 fragments directly
//     (no cvt VALU, 64 VGPR in flight). Raw f32 publish kept for slow path.
//   - u=0 A-path: plain C float4 loads from states (pure input).
//   - generation-slot barrier unchanged (harness poison negative as int).
constexpr int JT   = 16;            // j-columns per block
constexpr int NBLK = cN / JT;       // 32 blocks
constexpr int NT   = 1024;          // 16 waves
constexpr int NCW  = 4;             // compute waves (wave mt owns batch tile)
constexpr int SLOT_STRIDE = 16;     // ints; 64 B slot spacing

// ws layout (float offsets)
constexpr size_t OFF_V0   = 0;                            // [B][N] f32 ping
constexpr size_t OFF_V1   = (size_t)cB * cN;              // [B][N] f32 pong
constexpr size_t OFF_H0   = OFF_V1 + (size_t)cB * cN;     // [B][N] f16 ping (16K floats)
constexpr size_t OFF_H1   = OFF_H0 + (size_t)cB * cN / 2; // [B][N] f16 pong
constexpr size_t OFF_SLOT = OFF_H1 + (size_t)cB * cN / 2; // 32 slots x 16 ints

typedef _Float16 half8 __attribute__((ext_vector_type(8)));
typedef float    floatx4 __attribute__((ext_vector_type(4)));

__device__ __forceinline__ float clamp01(float x) {
    return __builtin_amdgcn_fmed3f(x, 0.0f, 1.0f);
}

// Gather one [512 x 16] weight-pair slice into LDS fragment layout (f16),
// fusing the sigma/mu uniformity probe. H[0..8191] = E*mask halves,
// H[8192..16383] = W*mask halves; frag f = kk*64 + lg*16 + lr, elem t:
// half index f*8 + t, with i = kk*32 + lg*8 + t, j = j0 + lr.
// NT=1024: q = tid&3 (16B column quarter), r0 = tid>>2 (row 0..255), 2 rows/thread.
__device__ __forceinline__ void gather_slice(
    const float* __restrict__ E,  const float* __restrict__ W,
    const float* __restrict__ SG, const float* __restrict__ MU,
    const float* __restrict__ MK,
    int j0, int tid, _Float16* H, int* badFlag)
{
    const int q = tid & 3, r0 = tid >> 2;
    bool bad = false;
#pragma unroll
    for (int p = 0; p < 2; ++p) {
        const int i = p * 256 + r0;
        const size_t o = (size_t)i * cN + j0 + q * 4;
        const float4 e4  = *(const float4*)(E + o);
        const float4 w4  = *(const float4*)(W + o);
        const float4 m4  = *(const float4*)(MK + o);
        const float4 sg4 = *(const float4*)(SG + o);
        const float4 mu4 = *(const float4*)(MU + o);
        if ((m4.x != 0.f && (sg4.x != 0.5f || mu4.x != 0.5f)) ||
            (m4.y != 0.f && (sg4.y != 0.5f || mu4.y != 0.5f)) ||
            (m4.z != 0.f && (sg4.z != 0.5f || mu4.z != 0.5f)) ||
            (m4.w != 0.f && (sg4.w != 0.5f || mu4.w != 0.5f))) bad = true;
        const int base = (((i >> 5) * 64) + (((i >> 3) & 3) * 16) + q * 4) * 8
                         + (i & 7);
        H[base +  0] = (_Float16)(e4.x * m4.x);
        H[base +  8] = (_Float16)(e4.y * m4.y);
        H[base + 16] = (_Float16)(e4.z * m4.z);
        H[base + 24] = (_Float16)(e4.w * m4.w);
        H[8192 + base +  0] = (_Float16)(w4.x * m4.x);
        H[8192 + base +  8] = (_Float16)(w4.y * m4.y);
        H[8192 + base + 16] = (_Float16)(w4.z * m4.z);
        H[8192 + base + 24] = (_Float16)(w4.w * m4.w);
    }
    if (bad) *badFlag = 1;   // benign LDS race (same value)
}

__global__ __launch_bounds__(NT, 1)
void k_fused(const float* __restrict__ inputs, const float* __restrict__ states,
             const float* __restrict__ tau,    const float* __restrict__ bias,
             const float* __restrict__ erev,   const float* __restrict__ wgt,
             const float* __restrict__ sigma,  const float* __restrict__ mu,
             const float* __restrict__ serev,  const float* __restrict__ swgt,
             const float* __restrict__ ssigma, const float* __restrict__ smu,
             const float* __restrict__ mask,   const float* __restrict__ smask,
             const float* __restrict__ inw,    const float* __restrict__ inb,
             const float* __restrict__ outw,   const float* __restrict__ outb,
             float* __restrict__ out, float* __restrict__ ws)
{
    float* v0 = ws + OFF_V0;
    float* v1 = ws + OFF_V1;
    _Float16* h0 = (_Float16*)(ws + OFF_H0);
    _Float16* h1 = (_Float16*)(ws + OFF_H1);
    int* slots = (int*)(ws + OFF_SLOT);

    const int tid  = threadIdx.x;
    const int blk  = blockIdx.x;
    const int j0   = blk * JT;
    const int lane = tid & 63;
    const int wv   = tid >> 6;          // wave id 0..15; compute waves: wv < 4
    const int mt   = wv;                // M-tile (batch group of 16) for compute
    const int lr   = lane & 15;         // row/col index within 16x16 tile
    const int lg   = lane >> 4;         // k-group (A/B), row-group (C/D)
    const int bj   = j0 + lr;           // this lane's output column j (B/C)
    const int arow = mt * 16 + lr;      // this lane's A-fragment row (batch)
    const int kbase = lg * 8;           // k offset inside a K=32 step
    const int cb0  = mt * 16 + lg * 4;  // first owned batch row (C mapping)

    int* mySlot = slots + blk * SLOT_STRIDE;

    // 64 KB LDS fragment table:
    //   halves [0,8192)      recurrent E*mask   [8192,16384)  recurrent W*mask
    //   halves [16384,24576) sensory  E*mask    [24576,32768) sensory  W*mask
    __shared__ _Float16 Hlds[32768];
    __shared__ int sBad[2];             // [0]=recurrent, [1]=sensory
    const half8* hfr = (const half8*)Hlds;

    if (tid < 2) sBad[tid] = 0;
    __syncthreads();                    // init visible before probe writes

    // ---- per-lane owned cells (compute waves): (b = cb0+r, j = bj) ----
    float vold[4] = {0.f, 0.f, 0.f, 0.f};
    float tau_j = 0.f, bias_j = 0.f, ow = 0.f, ob = 0.f;
    if (wv < NCW) {
#pragma unroll
        for (int r = 0; r < 4; ++r)
            vold[r] = states[(size_t)(cb0 + r) * cN + bj];
        tau_j  = tau[bj];
        bias_j = bias[bj];
        if (bj >= cN - cM) { ow = outw[bj - (cN - cM)]; ob = outb[bj - (cN - cM)]; }
    }

    // ---- gather both weight slices (all 1024 threads; plain cached loads) ----
    gather_slice(erev,  wgt,  sigma,  mu,  mask,  j0, tid, Hlds,         &sBad[0]);
    gather_slice(serev, swgt, ssigma, smu, smask, j0, tid, Hlds + 16384, &sBad[1]);
    __syncthreads();
    const bool fastR = (sBad[0] == 0);
    const bool fastS = (sBad[1] == 0);

    // ---- sensory reduction -> srb (s_rev + bias), swv (s_w) ----
    float srb[4] = {0.f, 0.f, 0.f, 0.f}, swv[4] = {0.f, 0.f, 0.f, 0.f};
    if (wv < NCW) {
        if (fastS) {
            floatx4 aR = {0.f, 0.f, 0.f, 0.f}, aW = {0.f, 0.f, 0.f, 0.f};
#pragma unroll
            for (int kk = 0; kk < 16; ++kk) {
                const int off = kk * 32 + kbase;
                const float4 xa = *(const float4*)(inputs + (size_t)arow * cS + off);
                const float4 xb = *(const float4*)(inputs + (size_t)arow * cS + off + 4);
                const float4 wa = *(const float4*)(inw + off);
                const float4 wb = *(const float4*)(inw + off + 4);
                const float4 ba = *(const float4*)(inb + off);
                const float4 bb = *(const float4*)(inb + off + 4);
                half8 ax;
                ax[0] = (_Float16)clamp01(fmaf(xa.x, wa.x, ba.x));
                ax[1] = (_Float16)clamp01(fmaf(xa.y, wa.y, ba.y));
                ax[2] = (_Float16)clamp01(fmaf(xa.z, wa.z, ba.z));
                ax[3] = (_Float16)clamp01(fmaf(xa.w, wa.w, ba.w));
                ax[4] = (_Float16)clamp01(fmaf(xb.x, wb.x, bb.x));
                ax[5] = (_Float16)clamp01(fmaf(xb.y, wb.y, bb.y));
                ax[6] = (_Float16)clamp01(fmaf(xb.z, wb.z, bb.z));
                ax[7] = (_Float16)clamp01(fmaf(xb.w, wb.w, bb.w));
                aR = __builtin_amdgcn_mfma_f32_16x16x32_f16(ax, hfr[2048 + kk * 64 + lane], aR, 0, 0, 0);
                aW = __builtin_amdgcn_mfma_f32_16x16x32_f16(ax, hfr[3072 + kk * 64 + lane], aW, 0, 0, 0);
            }
#pragma unroll
            for (int r = 0; r < 4; ++r) { srb[r] = aR[r] + bias_j; swv[r] = aW[r]; }
        } else {
            // general sensory path (slow, correct, unexercised by the bench)
            float sr4[4] = {0,0,0,0}, sw4[4] = {0,0,0,0};
            for (int s = 0; s < cS; ++s) {
                size_t o = (size_t)s * cN + bj;
                float mk = smask[o];
                float sg = ssigma[o];
                float a  = 0.5f / sg;
                float c  = fmaf(-smu[o], a, 0.5f);
                float ee = serev[o] * mk, ww = swgt[o] * mk;
                float iw = inw[s], ib = inb[s];
#pragma unroll
                for (int r = 0; r < 4; ++r) {
                    float x = fmaf(inputs[(size_t)(cb0 + r) * cS + s], iw, ib);
                    float g = clamp01(fmaf(x, a, c));
                    sr4[r] = fmaf(g, ee, sr4[r]);
                    sw4[r] = fmaf(g, ww, sw4[r]);
                }
            }
#pragma unroll
            for (int r = 0; r < 4; ++r) { srb[r] = sr4[r] + bias_j; swv[r] = sw4[r]; }
        }
    }

    // ---- 6 unfolds; unfold 0 reads `states` directly ----
    for (int u = 0; u < cUNF; ++u) {
        const float*    vRp = (u == 0) ? states : ((u & 1) ? v0 : v1);
        const _Float16* hRp = (u & 1) ? h0 : h1;   // valid for u >= 1

        float sumE[4], sumW[4];
        if (wv < NCW) {
            if (fastR) {
                floatx4 aE = {0.f, 0.f, 0.f, 0.f}, aWc = {0.f, 0.f, 0.f, 0.f};
                if (u == 0) {
                    // plain cached float4 loads from states (pure input)
                    const float* vrow = states + (size_t)arow * cN + kbase;
#pragma unroll
                    for (int kk = 0; kk < 16; ++kk) {
                        const float4 va = *(const float4*)(vrow + kk * 32);
                        const float4 vb = *(const float4*)(vrow + kk * 32 + 4);
                        half8 a8;
                        a8[0] = (_Float16)clamp01(va.x);
                        a8[1] = (_Float16)clamp01(va.y);
                        a8[2] = (_Float16)clamp01(va.z);
                        a8[3] = (_Float16)clamp01(va.w);
                        a8[4] = (_Float16)clamp01(vb.x);
                        a8[5] = (_Float16)clamp01(vb.y);
                        a8[6] = (_Float16)clamp01(vb.z);
                        a8[7] = (_Float16)clamp01(vb.w);
                        aE  = __builtin_amdgcn_mfma_f32_16x16x32_f16(a8, hfr[kk * 64 + lane], aE,  0, 0, 0);
                        aWc = __builtin_amdgcn_mfma_f32_16x16x32_f16(a8, hfr[1024 + kk * 64 + lane], aWc, 0, 0, 0);
                    }
                } else {
                    // A-gather: 16 pipelined 16B gated-f16 loads, ONE waitcnt.
                    floatx4 raw[16];
                    const _Float16* hrow = hRp + (size_t)arow * cN + kbase;
#pragma unroll
                    for (int kk = 0; kk < 16; ++kk)
                        asm volatile("global_load_dwordx4 %0, %1, off offset:%2 sc0 sc1"
                                     : "=v"(raw[kk]) : "v"(hrow), "n"(kk * 64) : "memory");
                    asm volatile("s_waitcnt vmcnt(0)" ::: "memory");
                    __builtin_amdgcn_sched_barrier(0);   // rule #18
#pragma unroll
                    for (int kk = 0; kk < 16; ++kk) {
                        const half8 a8 = __builtin_bit_cast(half8, raw[kk]);
                        aE  = __builtin_amdgcn_mfma_f32_16x16x32_f16(a8, hfr[kk * 64 + lane], aE,  0, 0, 0);
                        aWc = __builtin_amdgcn_mfma_f32_16x16x32_f16(a8, hfr[1024 + kk * 64 + lane], aWc, 0, 0, 0);
                    }
                }
#pragma unroll
                for (int r = 0; r < 4; ++r) { sumE[r] = aE[r]; sumW[r] = aWc[r]; }
            } else {
                // general recurrent path (slow, correct): reads raw f32 v
                float r4[4] = {0,0,0,0}, w4[4] = {0,0,0,0};
                for (int i = 0; i < cN; ++i) {
                    size_t o = (size_t)i * cN + bj;
                    float mk = mask[o];
                    float sg = sigma[o];
                    float a  = 0.5f / sg;
                    float c  = fmaf(-mu[o], a, 0.5f);
                    float ee = erev[o] * mk, ww = wgt[o] * mk;
#pragma unroll
                    for (int r = 0; r < 4; ++r) {
                        float vi = __hip_atomic_load(&vRp[(size_t)(cb0 + r) * cN + i],
                                                     __ATOMIC_RELAXED, __HIP_MEMORY_SCOPE_AGENT);
                        float g = clamp01(fmaf(vi, a, c));
                        r4[r] = fmaf(g, ee, r4[r]);
                        w4[r] = fmaf(g, ww, w4[r]);
                    }
                }
#pragma unroll
                for (int r = 0; r < 4; ++r) { sumE[r] = r4[r]; sumW[r] = w4[r]; }
            }

            // v update for owned cells (all state in registers)
#pragma unroll
            for (int r = 0; r < 4; ++r) {
                float rr   = sumE[r] + srb[r];
                float wsum = sumW[r] + swv[r];
                float k    = 1.0f / (1.0f + wsum);
                float taun = tau_j * k;
                float inv  = 1.0f / (taun + cDELTA);
                float vn   = (taun * inv) * vold[r] + (cDELTA * inv) * k * rr;
                vold[r] = vn;
            }
        }

        if (u < cUNF - 1) {
            // publish v(u+1) (raw f32 for slow readers, gated f16 for fast);
            // generation barrier gen u+1 (1..5). Safety: slot store follows a
            // __syncthreads that drains all prior memory ops (incl. this
            // block's reads of the buffer being recycled).
            if (wv < NCW) {
                float*    vWp = (u & 1) ? v1 : v0;
                _Float16* hWp = (u & 1) ? h1 : h0;
#pragma unroll
                for (int r = 0; r < 4; ++r) {
                    __hip_atomic_store(&vWp[(size_t)(cb0 + r) * cN + bj], vold[r],
                                       __ATOMIC_RELAXED, __HIP_MEMORY_SCOPE_AGENT);
                    _Float16 g = (_Float16)clamp01(vold[r]);
                    unsigned short gs;
                    memcpy(&gs, &g, 2);
                    unsigned int gi = gs;
                    asm volatile("global_store_short %0, %1, off sc0 sc1"
                                 :: "v"(hWp + (size_t)(cb0 + r) * cN + bj), "v"(gi)
                                 : "memory");
                }
            }
            __syncthreads();               // vmcnt(0) drain of the publishes
            if (tid == 0)
                __hip_atomic_store(mySlot, u + 1,
                                   __ATOMIC_RELAXED, __HIP_MEMORY_SCOPE_AGENT);
            if (tid < NBLK) {
                const int* sl = slots + tid * SLOT_STRIDE;
                while (__hip_atomic_load(sl, __ATOMIC_RELAXED,
                                         __HIP_MEMORY_SCOPE_AGENT) < u + 1)
                    __builtin_amdgcn_s_sleep(1);
            }
            __syncthreads();
        }
    }

    // ---- epilogue: final v + mapped outputs ----
    if (wv < NCW) {
        float* vout = out + (size_t)cB * cM;
#pragma unroll
        for (int r = 0; r < 4; ++r) {
            int b = cb0 + r;
            vout[(size_t)b * cN + bj] = vold[r];
            if (bj >= cN - cM)
                out[(size_t)b * cM + (bj - (cN - cM))] = fmaf(vold[r], ow, ob);
        }
    }
}

extern "C" void kernel_launch(void* const* d_in, const int* in_sizes, int n_in,
                              void* d_out, int out_size, void* d_ws, size_t ws_size,
                              hipStream_t stream)
{
    const float* inputs = (const float*)d_in[0];
    const float* states = (const float*)d_in[1];
    const float* tau    = (const float*)d_in[2];
    const float* bias   = (const float*)d_in[3];
    const float* erev   = (const float*)d_in[4];
    const float* wgt    = (const float*)d_in[5];
    const float* sigma  = (const float*)d_in[6];
    const float* mu     = (const float*)d_in[7];
    const float* serev  = (const float*)d_in[8];
    const float* swgt   = (const float*)d_in[9];
    const float* ssigma = (const float*)d_in[10];
    const float* smu    = (const float*)d_in[11];
    const float* mask   = (const float*)d_in[12];
    const float* smask  = (const float*)d_in[13];
    const float* inw    = (const float*)d_in[14];
    const float* inb    = (const float*)d_in[15];
    const float* outw   = (const float*)d_in[16];
    const float* outb   = (const float*)d_in[17];
    float* out = (float*)d_out;
    float* ws  = (float*)d_ws;

    // Single dispatch: 32 blocks x 1024 threads, trivially co-resident on
    // 256 CUs -> internal generation-slot barriers cannot deadlock. Slot
    // generations start from harness poison (negative as int); no memset.
    k_fused<<<NBLK, NT, 0, stream>>>(inputs, states, tau, bias, erev, wgt,
                                     sigma, mu, serev, swgt, ssigma, smu,
                                     mask, smask, inw, inb, outw, outb,
                                     out, ws);
}